// Round 4
// baseline (641.207 us; speedup 1.0000x reference)
//
#include <hip/hip_runtime.h>
#include <hip/hip_cooperative_groups.h>
#include <hip/hip_bf16.h>
#include <math.h>

namespace cg = cooperative_groups;

typedef unsigned short u16;
typedef short bf16x8 __attribute__((ext_vector_type(8)));
typedef float f32x4 __attribute__((ext_vector_type(4)));
typedef float f32x16 __attribute__((ext_vector_type(16)));

__device__ __forceinline__ u16 f2b(float f){
  union { float f; unsigned u; } c; c.f = f;
  unsigned u = c.u;
  unsigned r = (u + 0x7fffu + ((u >> 16) & 1u)) >> 16;
  return (u16)r;
}
__device__ __forceinline__ unsigned pack2(float a, float b){
  return (unsigned)f2b(a) | ((unsigned)f2b(b) << 16);
}
__device__ __forceinline__ float gelu_f(float x){
  return 0.5f * x * (1.0f + erff(x * 0.70710678118654752f));
}

// ---------------------------------------------------------------------------
// Phase: weight prep -> bf16 [N][K] row-major + zero stats.
// wT layout (u16): WprojT@0 (128x128) | QKVT@16384 (2 x [1536][128]) |
// WhT@409600 (2 x [128][512]) | WfcT@540672 (2 x [128][128]) | WcT@573440.
// ---------------------------------------------------------------------------
__device__ void dev_prep(
    const float* __restrict__ Wproj, const float* __restrict__ Wq,
    const float* __restrict__ Wk,    const float* __restrict__ Wv,
    const float* __restrict__ Whp,   const float* __restrict__ Wfc,
    const float* __restrict__ Wc,    u16* __restrict__ wT,
    float* __restrict__ stats)
{
  for (int gid = blockIdx.x * 256 + threadIdx.x; gid < 639360; gid += gridDim.x * 256) {
    if (gid >= 638976) { stats[gid - 638976] = 0.0f; continue; }
    float val;
    if (gid < 16384) {
      int n = gid >> 7, k = gid & 127;
      val = Wproj[k * 128 + n];
    } else if (gid < 409600) {               // fused QKV^T
      int o = gid - 16384; int l = o / 196608, oo = o - l * 196608;
      int n = oo >> 7, k = oo & 127;
      if (n < 512)       val = Wq[l * 65536 + k * 512 + n];
      else if (n < 1024) val = Wk[l * 65536 + k * 512 + (n - 512)];
      else               val = Wv[l * 65536 + k * 512 + (n - 1024)];
    } else if (gid < 540672) {               // WhT[l][n][k], in [512][128]
      int o = gid - 409600; int l = o >> 16, oo = o & 65535;
      int n = oo >> 9, k = oo & 511;
      val = Whp[l * 65536 + k * 128 + n];
    } else if (gid < 573440) {               // WfcT
      int o = gid - 540672; int l = o >> 14, oo = o & 16383;
      int n = oo >> 7, k = oo & 127;
      val = Wfc[l * 16384 + k * 128 + n];
    } else {                                 // WcT[n][k], in [128][512]
      int o = gid - 573440; int n = o >> 7, k = o & 127;
      val = Wc[k * 512 + n];
    }
    wT[gid] = f2b(val);
  }
}

// ---------------------------------------------------------------------------
// Phase: generic GEMM C[Mx?] = A[MxK] @ Bt[?xK]^T. 64x64 tile, grid-stride.
// A-staging: mode 1 -> from f32 x (f2b + row validity); stA -> normalized f32;
// else bf16 A. Epilogues as before (1 gelu+mask, 4 add+mask+stats,
// 5 gelu-add+mask+stats, 6 qkv split).
// ---------------------------------------------------------------------------
__device__ void dev_gemm(u16* LDSu, float* s_red, float* s_svalid,
    int ntiles, int NBN,
    const u16* __restrict__ A, const float* __restrict__ Af,
    const float* __restrict__ stA, const u16* __restrict__ Bt,
    float* __restrict__ outf, u16* __restrict__ outb,
    u16* __restrict__ outb2, u16* __restrict__ outb3,
    const float* __restrict__ hin, const float* __restrict__ hst,
    float* __restrict__ valid, float* __restrict__ stats,
    const int* __restrict__ xsize, int K, int mode)
{
  u16* As = LDSu;
  u16* Bs = LDSu + 8704;
  int tid = threadIdx.x;
  int wave = tid >> 6, lane = tid & 63, quad = lane >> 4, l16 = lane & 15;
  int wm = (wave >> 1) * 32, wn = (wave & 1) * 32;
  for (int tile = blockIdx.x; tile < ntiles; tile += gridDim.x) {
    int bm = tile / NBN, bn = tile - bm * NBN;
    int sset = bm >> 1;
    __syncthreads();   // protect LDS reuse across tiles/phases
    float amean = 0.f, ainv = 0.f, hmean = 0.f, hinv = 0.f;
    if (stA) {
      float S1 = stA[sset * 2], S2 = stA[sset * 2 + 1];
      int sz = xsize[sset]; if (sz < 1) sz = 1;
      float den = (float)sz * 128.0f;
      float mu = S1 / den; float var = S2 / den - mu * mu; if (var < 0.f) var = 0.f;
      amean = mu; ainv = 1.0f / (sqrtf(var) + 1e-8f);
    }
    if (hst) {
      float S1 = hst[sset * 2], S2 = hst[sset * 2 + 1];
      int sz = xsize[sset]; if (sz < 1) sz = 1;
      float den = (float)sz * 128.0f;
      float mu = S1 / den; float var = S2 / den - mu * mu; if (var < 0.f) var = 0.f;
      hmean = mu; hinv = 1.0f / (sqrtf(var) + 1e-8f);
    }
    f32x4 acc[2][2] = {};
    int nk = K >> 7;
    for (int kk = 0; kk < nk; ++kk) {
      for (int i = 0; i < 4; ++i) {
        int ch = tid + i * 256;
        int r = ch >> 4, cc = ch & 15;
        int row = bm * 64 + r;
        if (mode == 1) {
          const float* p = Af + (size_t)row * 128 + cc * 8;
          float4 u0 = *(const float4*)p;
          float4 u1 = *(const float4*)(p + 4);
          int nz = (u0.x != 0.f) | (u0.y != 0.f) | (u0.z != 0.f) | (u0.w != 0.f) |
                   (u1.x != 0.f) | (u1.y != 0.f) | (u1.z != 0.f) | (u1.w != 0.f);
          nz |= __shfl_xor(nz, 1, 64); nz |= __shfl_xor(nz, 2, 64);
          nz |= __shfl_xor(nz, 4, 64); nz |= __shfl_xor(nz, 8, 64);
          if ((tid & 15) == 0) {
            s_svalid[r] = nz ? 1.0f : 0.0f;
            if (bn == 0) valid[row] = nz ? 1.0f : 0.0f;
          }
          uint4 w;
          w.x = pack2(u0.x, u0.y); w.y = pack2(u0.z, u0.w);
          w.z = pack2(u1.x, u1.y); w.w = pack2(u1.z, u1.w);
          *(uint4*)(As + r * 136 + cc * 8) = w;
        } else if (stA) {
          const float* p = Af + (size_t)row * 128 + cc * 8;
          float vl = valid[row] * ainv;
          float4 u0 = *(const float4*)p;
          float4 u1 = *(const float4*)(p + 4);
          uint4 w;
          w.x = pack2((u0.x - amean) * vl, (u0.y - amean) * vl);
          w.y = pack2((u0.z - amean) * vl, (u0.w - amean) * vl);
          w.z = pack2((u1.x - amean) * vl, (u1.y - amean) * vl);
          w.w = pack2((u1.z - amean) * vl, (u1.w - amean) * vl);
          *(uint4*)(As + r * 136 + cc * 8) = w;
        } else {
          *(uint4*)(As + r * 136 + cc * 8) =
              *(const uint4*)(A + (size_t)row * K + kk * 128 + cc * 8);
        }
        *(uint4*)(Bs + r * 136 + cc * 8) =
            *(const uint4*)(Bt + (size_t)(bn * 64 + r) * K + kk * 128 + cc * 8);
      }
      __syncthreads();
      for (int ks = 0; ks < 4; ++ks) {
        bf16x8 aF[2], bF[2];
        for (int i = 0; i < 2; ++i)
          aF[i] = *(const bf16x8*)(As + (wm + i * 16 + l16) * 136 + ks * 32 + quad * 8);
        for (int j = 0; j < 2; ++j)
          bF[j] = *(const bf16x8*)(Bs + (wn + j * 16 + l16) * 136 + ks * 32 + quad * 8);
        for (int i = 0; i < 2; ++i)
          for (int j = 0; j < 2; ++j)
            acc[i][j] = __builtin_amdgcn_mfma_f32_16x16x32_bf16(aF[i], bF[j], acc[i][j], 0, 0, 0);
      }
      __syncthreads();
    }
    float ls1 = 0.f, ls2 = 0.f;
    for (int i = 0; i < 2; ++i)
      for (int j = 0; j < 2; ++j)
        for (int g = 0; g < 4; ++g) {
          int rl = wm + i * 16 + quad * 4 + g;
          int r = bm * 64 + rl;
          int c = bn * 64 + wn + j * 16 + l16;
          float a = acc[i][j][g];
          if (mode == 1) {
            float gg = gelu_f(a) * s_svalid[rl];
            outf[(size_t)r * 128 + c] = gg;
            outb[(size_t)r * 128 + c] = f2b(gg);
          } else if (mode == 4 || mode == 5) {
            float add = (mode == 5) ? gelu_f(a) : a;
            float vl = valid[r];
            float hv = hin[(size_t)r * 128 + c];
            if (hst) hv = (hv - hmean) * hinv * vl;
            float u = hv + add * vl;
            outf[(size_t)r * 128 + c] = u;
            ls1 += u; ls2 += u * u;
          } else { // mode 6
            int s = r >> 7, m = r & 127;
            if (c < 512) {
              int hh = c >> 7, d = c & 127;
              outb[(size_t)(((s * 4 + hh) * 128 + m)) * 128 + d] = f2b(a);
            } else if (c < 1024) {
              int c2 = c - 512, hh = c2 >> 7, d = c2 & 127;
              outb2[(size_t)(((s * 4 + hh) * 128 + m)) * 128 + d] = f2b(a);
            } else {
              int c2 = c - 1024, hh = c2 >> 7, d = c2 & 127;
              outb3[(size_t)(((s * 4 + hh) * 128 + d)) * 128 + m] = f2b(a);
            }
          }
        }
    if (mode == 4 || mode == 5) {
      for (int off = 1; off < 64; off <<= 1) {
        ls1 += __shfl_xor(ls1, off, 64);
        ls2 += __shfl_xor(ls2, off, 64);
      }
      if (lane == 0) { s_red[wave * 2] = ls1; s_red[wave * 2 + 1] = ls2; }
      __syncthreads();
      if (tid == 0) {
        float S1 = s_red[0] + s_red[2] + s_red[4] + s_red[6];
        float S2 = s_red[1] + s_red[3] + s_red[5] + s_red[7];
        atomicAdd(stats + sset * 2, S1);
        atomicAdd(stats + sset * 2 + 1, S2);
      }
    }
  }
}

// ---------------------------------------------------------------------------
// Phase: attention per (set, head) tile, size-trimmed (R2/R3-proven body).
// ---------------------------------------------------------------------------
__device__ void dev_attn(u16* LDSu,
    const u16* __restrict__ qg, const u16* __restrict__ kg,
    const u16* __restrict__ vTg, u16* __restrict__ og,
    const int* __restrict__ xsize)
{
  u16* bufA = LDSu;
  u16* bufB = LDSu + 17408;
  int tid = threadIdx.x, wave = tid >> 6, lane = tid & 63, quad = lane >> 4, l16 = lane & 15;
  for (int bid = blockIdx.x; bid < 192; bid += gridDim.x) {
    int s = bid >> 2, hh = bid & 3;
    int sz = xsize[s]; if (sz < 1) sz = 1;
    int Mt = (sz + 15) >> 4;
    int Mk = (sz + 31) >> 5;
    size_t base = (size_t)bid * 16384;
    __syncthreads();
    for (int t = 0; t < 8; ++t) {
      if (t < Mt) {
        int ch = tid + t * 256; int r = ch >> 4, cc = ch & 15;
        *(uint4*)(bufA + r * 136 + cc * 8) = *(const uint4*)(qg + base + r * 128 + cc * 8);
        *(uint4*)(bufB + r * 136 + cc * 8) = *(const uint4*)(kg + base + r * 128 + cc * 8);
      }
    }
    __syncthreads();
    int wm = wave * 32;
    bool act0 = (wave * 2) < Mt, act1 = (wave * 2 + 1) < Mt;
    f32x4 acc[2][8] = {};
    if (act0 || act1) {
      for (int ks = 0; ks < 4; ++ks) {
        bf16x8 aF[2], bF[8];
        if (act0) aF[0] = *(const bf16x8*)(bufA + (wm + l16) * 136 + ks * 32 + quad * 8);
        if (act1) aF[1] = *(const bf16x8*)(bufA + (wm + 16 + l16) * 136 + ks * 32 + quad * 8);
#pragma unroll
        for (int j = 0; j < 8; ++j)
          if (j < Mt) bF[j] = *(const bf16x8*)(bufB + (j * 16 + l16) * 136 + ks * 32 + quad * 8);
#pragma unroll
        for (int j = 0; j < 8; ++j)
          if (j < Mt) {
            if (act0) acc[0][j] = __builtin_amdgcn_mfma_f32_16x16x32_bf16(aF[0], bF[j], acc[0][j], 0, 0, 0);
            if (act1) acc[1][j] = __builtin_amdgcn_mfma_f32_16x16x32_bf16(aF[1], bF[j], acc[1][j], 0, 0, 0);
          }
      }
    }
    const float rs = 0.08838834764831845f;
    for (int i = 0; i < 2; ++i) {
      bool act = i ? act1 : act0;
      if (!act) continue;
      for (int g = 0; g < 4; ++g) {
        int rl = wm + i * 16 + quad * 4 + g;
        float vals[8]; float rmax = -1e30f;
#pragma unroll
        for (int j = 0; j < 8; ++j)
          if (j < Mt) {
            float v = acc[i][j][g] * rs;
            vals[j] = v;
            rmax = fmaxf(rmax, v);
          }
        for (int off = 1; off < 16; off <<= 1) rmax = fmaxf(rmax, __shfl_xor(rmax, off, 64));
        if (sz < 128) rmax = fmaxf(rmax, 0.0f);  // reference max includes pad zeros
        float rsum = 0.f;
#pragma unroll
        for (int j = 0; j < 8; ++j)
          if (j < Mt) {
            float e = (vals[j] != 0.0f) ? expf(vals[j] - rmax) : 0.0f;
            vals[j] = e; rsum += e;
          }
        for (int off = 1; off < 16; off <<= 1) rsum += __shfl_xor(rsum, off, 64);
        float inv = 1.0f / (rsum + 1e-10f);
#pragma unroll
        for (int j = 0; j < 8; ++j)
          if (j < Mt) bufA[rl * 136 + j * 16 + l16] = f2b(vals[j] * inv);
      }
    }
    __syncthreads();
    for (int t = 0; t < 8; ++t) {
      int ch = tid + t * 256; int r = ch >> 4, cc = ch & 15;
      *(uint4*)(bufB + r * 136 + cc * 8) = *(const uint4*)(vTg + base + r * 128 + cc * 8);
    }
    __syncthreads();
    f32x4 acc2[2][8] = {};
    if (act0 || act1) {
      for (int ks = 0; ks < Mk; ++ks) {
        bf16x8 aF[2], bF[8];
        if (act0) aF[0] = *(const bf16x8*)(bufA + (wm + l16) * 136 + ks * 32 + quad * 8);
        if (act1) aF[1] = *(const bf16x8*)(bufA + (wm + 16 + l16) * 136 + ks * 32 + quad * 8);
#pragma unroll
        for (int j = 0; j < 8; ++j)
          bF[j] = *(const bf16x8*)(bufB + (j * 16 + l16) * 136 + ks * 32 + quad * 8);
#pragma unroll
        for (int j = 0; j < 8; ++j) {
          if (act0) acc2[0][j] = __builtin_amdgcn_mfma_f32_16x16x32_bf16(aF[0], bF[j], acc2[0][j], 0, 0, 0);
          if (act1) acc2[1][j] = __builtin_amdgcn_mfma_f32_16x16x32_bf16(aF[1], bF[j], acc2[1][j], 0, 0, 0);
        }
      }
    }
    for (int i = 0; i < 2; ++i)
      for (int j = 0; j < 8; ++j)
        for (int g = 0; g < 4; ++g) {
          int rl = wm + i * 16 + quad * 4 + g;
          int d = j * 16 + l16;
          og[(size_t)(s * 128 + rl) * 512 + hh * 128 + d] = f2b(acc2[i][j][g]);
        }
  }
}

// ---------------------------------------------------------------------------
// Phase: cross-set, balanced (j<=i) pair tiles, grid-strided. 32x32x16 MFMA,
// fragment-order LDS (lane-linear, conflict-free). leaky = 0.65x + 0.35|x|.
// Writes raw symmetric sum T[j,i,h]; final divides per direction.
// ---------------------------------------------------------------------------
__device__ void dev_cross(u16* LDSu, float* s_red,
    const u16* __restrict__ zg, float* __restrict__ Tbuf,
    const int* __restrict__ xsize)
{
  u16* bufA = LDSu;
  u16* bufB = LDSu + 16384;
  int tid = threadIdx.x, wave = tid >> 6, lane = tid & 63;
  const float rs = 0.08838834764831845f;
  for (int t4 = blockIdx.x; t4 < 4704; t4 += gridDim.x) {
    int pr = t4 >> 2, hh = t4 & 3;
    int j = 0, rem = pr;
    while (rem >= 48 - j) { rem -= 48 - j; ++j; }
    int i = j + rem;
    int sj = xsize[j]; if (sj < 1) sj = 1;
    int si = xsize[i]; if (si < 1) si = 1;
    int MjT = (sj + 31) >> 5, MiT = (si + 31) >> 5;
    size_t basej = ((size_t)j * 4 + hh) << 14;
    size_t basei = ((size_t)i * 4 + hh) << 14;
    __syncthreads();
#pragma unroll
    for (int t = 0; t < 8; ++t) {
      int c = t * 256 + tid;
      int m = c & 31, half = (c >> 5) & 1, ks = (c >> 6) & 7, g = c >> 9;
      int row = g * 32 + m, col = ks * 16 + half * 8;
      if (g < MjT) *(uint4*)(bufA + c * 8) = *(const uint4*)(zg + basej + row * 128 + col);
      if (g < MiT) *(uint4*)(bufB + c * 8) = *(const uint4*)(zg + basei + row * 128 + col);
    }
    __syncthreads();
    int gA = (wave >> 1) * 2, gB = (wave & 1) * 2;
    bool a0 = gA < MjT, a1 = (gA + 1) < MjT;
    bool b0 = gB < MiT, b1 = (gB + 1) < MiT;
    f32x16 acc[2][2] = {};
    if ((a0 || a1) && (b0 || b1)) {
      for (int ks = 0; ks < 8; ++ks) {
        bf16x8 aF[2], bF[2];
        if (a0) aF[0] = *(const bf16x8*)(bufA + ((gA    ) * 8 + ks) * 512 + lane * 8);
        if (a1) aF[1] = *(const bf16x8*)(bufA + ((gA + 1) * 8 + ks) * 512 + lane * 8);
        if (b0) bF[0] = *(const bf16x8*)(bufB + ((gB    ) * 8 + ks) * 512 + lane * 8);
        if (b1) bF[1] = *(const bf16x8*)(bufB + ((gB + 1) * 8 + ks) * 512 + lane * 8);
        if (a0 && b0) acc[0][0] = __builtin_amdgcn_mfma_f32_32x32x16_bf16(aF[0], bF[0], acc[0][0], 0, 0, 0);
        if (a0 && b1) acc[0][1] = __builtin_amdgcn_mfma_f32_32x32x16_bf16(aF[0], bF[1], acc[0][1], 0, 0, 0);
        if (a1 && b0) acc[1][0] = __builtin_amdgcn_mfma_f32_32x32x16_bf16(aF[1], bF[0], acc[1][0], 0, 0, 0);
        if (a1 && b1) acc[1][1] = __builtin_amdgcn_mfma_f32_32x32x16_bf16(aF[1], bF[1], acc[1][1], 0, 0, 0);
      }
    }
    float s1 = 0.f, s2 = 0.f;
#pragma unroll
    for (int ii = 0; ii < 2; ++ii)
#pragma unroll
      for (int jj = 0; jj < 2; ++jj)
#pragma unroll
        for (int r = 0; r < 16; ++r) {
          float a = acc[ii][jj][r];
          s1 += a; s2 += fabsf(a);
        }
    float tp = rs * (0.65f * s1 + 0.35f * s2);
    for (int off = 1; off < 64; off <<= 1) tp += __shfl_xor(tp, off, 64);
    if (lane == 0) s_red[wave] = tp;
    __syncthreads();
    if (tid == 0)
      Tbuf[((j * 48 + i) << 2) + hh] = s_red[0] + s_red[1] + s_red[2] + s_red[3];
  }
}

__device__ void dev_final(
    const float* __restrict__ Tbuf, const float* __restrict__ w2,
    const int* __restrict__ xsize, float* __restrict__ out)
{
  for (int idx = blockIdx.x * 256 + threadIdx.x; idx < 2304; idx += gridDim.x * 256) {
    int a = idx / 48, b = idx - a * 48;
    int j = a < b ? a : b, i = a < b ? b : a;
    float t = 0.f;
    for (int h = 0; h < 4; ++h) t += Tbuf[((j * 48 + i) << 2) + h] * w2[h];
    int szb = xsize[b]; if (szb < 1) szb = 1;
    out[idx] = t / ((float)szb * 128.0f);
  }
}

// ---------------------------------------------------------------------------
// The cooperative mega-kernel: all 13 phases, grid.sync() between them.
// LDS union: attn needs 2x128x136 u16 = 34816 u16 (69632 B) -> 2 blocks/CU.
// ---------------------------------------------------------------------------
__global__ __launch_bounds__(256, 2) void mega(
    const float* x, const int* xsize, const float* Wproj, const float* Wq,
    const float* Wk, const float* Wv, const float* Whp, const float* Wfc,
    const float* Wc, const float* w2, float* out,
    u16* wT, float* stats, float* Tbuf, float* valid,
    float* hf0, u16* hb, float* ufA, float* ufB,
    u16* qb, u16* kb, u16* vTb, u16* ob)
{
  __shared__ __align__(16) u16 LDSu[34816];
  __shared__ float s_red[8];
  __shared__ float s_svalid[64];
  cg::grid_group grid = cg::this_grid();

  float* st00 = stats +   0;
  float* st01 = stats +  96;
  float* st10 = stats + 192;
  float* st11 = stats + 288;

  // P0: weights -> bf16 transposed, zero stats
  dev_prep(Wproj, Wq, Wk, Wv, Whp, Wfc, Wc, wT, stats);
  grid.sync();
  // P1: h0 = gelu(x @ Wproj) * mask  (also computes valid[])
  dev_gemm(LDSu, s_red, s_svalid, 192, 2, nullptr, x, nullptr, wT,
           hf0, hb, nullptr, nullptr, nullptr, nullptr, valid, nullptr, xsize, 128, 1);
  grid.sync();
  // ---- layer 0 ----
  dev_gemm(LDSu, s_red, s_svalid, 2304, 24, hb, nullptr, nullptr, wT + 16384,
           nullptr, qb, kb, vTb, nullptr, nullptr, valid, nullptr, xsize, 128, 6);
  grid.sync();
  dev_attn(LDSu, qb, kb, vTb, ob, xsize);
  grid.sync();
  dev_gemm(LDSu, s_red, s_svalid, 192, 2, ob, nullptr, nullptr, wT + 409600,
           ufA, nullptr, nullptr, nullptr, hf0, nullptr, valid, st00, xsize, 512, 4);
  grid.sync();
  dev_gemm(LDSu, s_red, s_svalid, 192, 2, nullptr, ufA, st00, wT + 540672,
           ufB, nullptr, nullptr, nullptr, ufA, st00, valid, st01, xsize, 128, 5);
  grid.sync();
  // ---- layer 1 ----
  dev_gemm(LDSu, s_red, s_svalid, 2304, 24, nullptr, ufB, st01, wT + 16384 + 196608,
           nullptr, qb, kb, vTb, nullptr, nullptr, valid, nullptr, xsize, 128, 6);
  grid.sync();
  dev_attn(LDSu, qb, kb, vTb, ob, xsize);
  grid.sync();
  dev_gemm(LDSu, s_red, s_svalid, 192, 2, ob, nullptr, nullptr, wT + 409600 + 65536,
           ufA, nullptr, nullptr, nullptr, ufB, st01, valid, st10, xsize, 512, 4);
  grid.sync();
  dev_gemm(LDSu, s_red, s_svalid, 192, 2, nullptr, ufA, st10, wT + 540672 + 16384,
           ufB, nullptr, nullptr, nullptr, ufA, st10, valid, st11, xsize, 128, 5);
  grid.sync();
  // ---- z = h @ Wc (q-layout), cross, final ----
  dev_gemm(LDSu, s_red, s_svalid, 768, 8, nullptr, ufB, st11, wT + 573440,
           nullptr, qb, qb, qb, nullptr, nullptr, valid, nullptr, xsize, 128, 6);
  grid.sync();
  dev_cross(LDSu, s_red, qb, Tbuf, xsize);
  grid.sync();
  dev_final(Tbuf, w2, xsize, out);
}

// ---------------------------------------------------------------------------
extern "C" void kernel_launch(void* const* d_in, const int* in_sizes, int n_in,
                              void* d_out, int out_size, void* d_ws, size_t ws_size,
                              hipStream_t stream)
{
  const float* x     = (const float*)d_in[0];
  const int*   xsize = (const int*)d_in[1];
  const float* Wproj = (const float*)d_in[2];
  const float* Wq    = (const float*)d_in[3];
  const float* Wk    = (const float*)d_in[4];
  const float* Wv    = (const float*)d_in[5];
  const float* Whp   = (const float*)d_in[6];
  const float* Wfc   = (const float*)d_in[7];
  const float* Wc    = (const float*)d_in[8];
  const float* w2    = (const float*)d_in[9];
  float* out = (float*)d_out;

  char* ws = (char*)d_ws;
  size_t off = 0;
  auto alloc = [&](size_t bytes) -> char* {
    char* p = ws + off;
    off += (bytes + 255) & ~(size_t)255;
    return p;
  };
  u16*   wT    = (u16*)  alloc(638976 * 2);
  float* stats = (float*)alloc(384 * 4);
  float* Tbuf  = (float*)alloc(9216 * 4);
  float* valid = (float*)alloc(6144 * 4);
  float* hf0   = (float*)alloc(6144 * 128 * 4);
  u16*   hb    = (u16*)  alloc(6144 * 128 * 2);
  float* ufA   = (float*)alloc(6144 * 128 * 4);
  float* ufB   = (float*)alloc(6144 * 128 * 4);
  u16*   qb    = (u16*)  alloc((size_t)3145728 * 2);
  u16*   kb    = (u16*)  alloc((size_t)3145728 * 2);
  u16*   vTb   = (u16*)  alloc((size_t)3145728 * 2);
  u16*   ob    = (u16*)  alloc((size_t)6144 * 512 * 2);

  // Co-residency: query occupancy (same result every call -> graph-safe).
  int nb = 0;
  if (hipOccupancyMaxActiveBlocksPerMultiprocessor(&nb, mega, 256, 0) != hipSuccess || nb < 1)
    nb = 1;
  if (nb > 2) nb = 2;          // LDS bounds it at 2; stay conservative
  int nblocks = nb * 256;      // 256 CUs on MI355X

  void* args[] = {
    (void*)&x, (void*)&xsize, (void*)&Wproj, (void*)&Wq, (void*)&Wk, (void*)&Wv,
    (void*)&Whp, (void*)&Wfc, (void*)&Wc, (void*)&w2, (void*)&out,
    (void*)&wT, (void*)&stats, (void*)&Tbuf, (void*)&valid,
    (void*)&hf0, (void*)&hb, (void*)&ufA, (void*)&ufB,
    (void*)&qb, (void*)&kb, (void*)&vTb, (void*)&ob
  };
  hipLaunchCooperativeKernel((void*)mega, dim3(nblocks), dim3(256), args, 0, stream);
}

// Round 5
// 280.336 us; speedup vs baseline: 2.2873x; 2.2873x over previous
//
#include <hip/hip_runtime.h>
#include <hip/hip_bf16.h>
#include <math.h>

typedef unsigned short u16;
typedef short bf16x8 __attribute__((ext_vector_type(8)));
typedef float f32x4 __attribute__((ext_vector_type(4)));
typedef float f32x16 __attribute__((ext_vector_type(16)));

__device__ __forceinline__ u16 f2b(float f){
  union { float f; unsigned u; } c; c.f = f;
  unsigned u = c.u;
  unsigned r = (u + 0x7fffu + ((u >> 16) & 1u)) >> 16;
  return (u16)r;
}
__device__ __forceinline__ unsigned pack2(float a, float b){
  return (unsigned)f2b(a) | ((unsigned)f2b(b) << 16);
}
__device__ __forceinline__ float gelu_f(float x){
  return 0.5f * x * (1.0f + erff(x * 0.70710678118654752f));
}

// ---------------------------------------------------------------------------
// Weight prep -> bf16 [N][K] row-major + zero stats.
// wT layout (u16): WprojT@0 (128x128) | QKVT@16384 (2 x [1536][128]) |
// WhT@409600 (2 x [128][512]) | WfcT@540672 (2 x [128][128]) | WcT@573440.
// ---------------------------------------------------------------------------
__global__ __launch_bounds__(256) void prep_weights(
    const float* __restrict__ Wproj, const float* __restrict__ Wq,
    const float* __restrict__ Wk,    const float* __restrict__ Wv,
    const float* __restrict__ Whp,   const float* __restrict__ Wfc,
    const float* __restrict__ Wc,    u16* __restrict__ wT,
    float* __restrict__ stats)
{
  int gid = blockIdx.x * 256 + threadIdx.x;
  if (gid >= 639360) return;
  if (gid >= 638976) { stats[gid - 638976] = 0.0f; return; }
  float val;
  if (gid < 16384) {
    int n = gid >> 7, k = gid & 127;
    val = Wproj[k * 128 + n];
  } else if (gid < 409600) {               // fused QKV^T
    int o = gid - 16384; int l = o / 196608, oo = o - l * 196608;
    int n = oo >> 7, k = oo & 127;
    if (n < 512)       val = Wq[l * 65536 + k * 512 + n];
    else if (n < 1024) val = Wk[l * 65536 + k * 512 + (n - 512)];
    else               val = Wv[l * 65536 + k * 512 + (n - 1024)];
  } else if (gid < 540672) {               // WhT[l][n][k], in [512][128]
    int o = gid - 409600; int l = o >> 16, oo = o & 65535;
    int n = oo >> 9, k = oo & 511;
    val = Whp[l * 65536 + k * 128 + n];
  } else if (gid < 573440) {               // WfcT
    int o = gid - 540672; int l = o >> 14, oo = o & 16383;
    int n = oo >> 7, k = oo & 127;
    val = Wfc[l * 16384 + k * 128 + n];
  } else {                                 // WcT[n][k], in [128][512]
    int o = gid - 573440; int n = o >> 7, k = o & 127;
    val = Wc[k * 512 + n];
  }
  wT[gid] = f2b(val);
}

// ---------------------------------------------------------------------------
// Generic GEMM: C[M x N] = A[M x K] @ Bt[N x K]^T. 64x64 tile, 256 thr.
// A-staging: mode 1 -> from f32 x (f2b + row validity); stA -> normalized f32;
// else bf16 A.
// Epilogues:
//  1 GELU_MASK : g=gelu(acc)*valid -> outf, outb              (N=128)
//  4 ADD_MASK  : u=hin'+acc*valid -> outf, + stats atomics    (N=128)
//  5 GELU_ADD  : u=hin'+gelu(acc)*valid -> outf, + stats      (N=128)
//     (hin' = hst ? normalize(hin, hst) : hin)
//  6 QKV split : c<512 -> q[s][h][m][d]; <1024 -> k[s][h][m][d];
//                else v^T via LDS transpose -> coalesced [s][h][d][m] stores
// ---------------------------------------------------------------------------
__global__ __launch_bounds__(256) void gemm_bt(
    const u16* __restrict__ A, const float* __restrict__ Af,
    const float* __restrict__ stA, const u16* __restrict__ Bt,
    float* __restrict__ outf, u16* __restrict__ outb,
    u16* __restrict__ outb2, u16* __restrict__ outb3,
    const float* __restrict__ hin, const float* __restrict__ hst,
    float* __restrict__ valid, float* __restrict__ stats,
    const int* __restrict__ xsize, int K, int mode)
{
  __shared__ __align__(16) u16 As[64 * 136];
  __shared__ __align__(16) u16 Bs[64 * 136];
  __shared__ float red[8];
  __shared__ float svalid[64];
  int tid = threadIdx.x;
  int wave = tid >> 6, lane = tid & 63, quad = lane >> 4, l16 = lane & 15;
  int bm = blockIdx.x, bn = blockIdx.y;
  int wm = (wave >> 1) * 32, wn = (wave & 1) * 32;
  int sset = bm >> 1;
  float amean = 0.f, ainv = 0.f, hmean = 0.f, hinv = 0.f;
  if (stA) {
    float S1 = stA[sset * 2], S2 = stA[sset * 2 + 1];
    int sz = xsize[sset]; if (sz < 1) sz = 1;
    float den = (float)sz * 128.0f;
    float mu = S1 / den; float var = S2 / den - mu * mu; if (var < 0.f) var = 0.f;
    amean = mu; ainv = 1.0f / (sqrtf(var) + 1e-8f);
  }
  if (hst) {
    float S1 = hst[sset * 2], S2 = hst[sset * 2 + 1];
    int sz = xsize[sset]; if (sz < 1) sz = 1;
    float den = (float)sz * 128.0f;
    float mu = S1 / den; float var = S2 / den - mu * mu; if (var < 0.f) var = 0.f;
    hmean = mu; hinv = 1.0f / (sqrtf(var) + 1e-8f);
  }
  f32x4 acc[2][2] = {};
  int nk = K >> 7;
  for (int kk = 0; kk < nk; ++kk) {
    for (int i = 0; i < 4; ++i) {
      int ch = tid + i * 256;
      int r = ch >> 4, cc = ch & 15;
      int row = bm * 64 + r;
      if (mode == 1) {
        const float* p = Af + (size_t)row * 128 + cc * 8;
        float4 u0 = *(const float4*)p;
        float4 u1 = *(const float4*)(p + 4);
        int nz = (u0.x != 0.f) | (u0.y != 0.f) | (u0.z != 0.f) | (u0.w != 0.f) |
                 (u1.x != 0.f) | (u1.y != 0.f) | (u1.z != 0.f) | (u1.w != 0.f);
        nz |= __shfl_xor(nz, 1, 64); nz |= __shfl_xor(nz, 2, 64);
        nz |= __shfl_xor(nz, 4, 64); nz |= __shfl_xor(nz, 8, 64);
        if ((tid & 15) == 0) {
          svalid[r] = nz ? 1.0f : 0.0f;
          if (bn == 0) valid[row] = nz ? 1.0f : 0.0f;
        }
        uint4 w;
        w.x = pack2(u0.x, u0.y); w.y = pack2(u0.z, u0.w);
        w.z = pack2(u1.x, u1.y); w.w = pack2(u1.z, u1.w);
        *(uint4*)(As + r * 136 + cc * 8) = w;
      } else if (stA) {
        const float* p = Af + (size_t)row * 128 + cc * 8;
        float vl = valid[row] * ainv;
        float4 u0 = *(const float4*)p;
        float4 u1 = *(const float4*)(p + 4);
        uint4 w;
        w.x = pack2((u0.x - amean) * vl, (u0.y - amean) * vl);
        w.y = pack2((u0.z - amean) * vl, (u0.w - amean) * vl);
        w.z = pack2((u1.x - amean) * vl, (u1.y - amean) * vl);
        w.w = pack2((u1.z - amean) * vl, (u1.w - amean) * vl);
        *(uint4*)(As + r * 136 + cc * 8) = w;
      } else {
        *(uint4*)(As + r * 136 + cc * 8) =
            *(const uint4*)(A + (size_t)row * K + kk * 128 + cc * 8);
      }
      *(uint4*)(Bs + r * 136 + cc * 8) =
          *(const uint4*)(Bt + (size_t)(bn * 64 + r) * K + kk * 128 + cc * 8);
    }
    __syncthreads();
    for (int ks = 0; ks < 4; ++ks) {
      bf16x8 aF[2], bF[2];
      for (int i = 0; i < 2; ++i)
        aF[i] = *(const bf16x8*)(As + (wm + i * 16 + l16) * 136 + ks * 32 + quad * 8);
      for (int j = 0; j < 2; ++j)
        bF[j] = *(const bf16x8*)(Bs + (wn + j * 16 + l16) * 136 + ks * 32 + quad * 8);
      for (int i = 0; i < 2; ++i)
        for (int j = 0; j < 2; ++j)
          acc[i][j] = __builtin_amdgcn_mfma_f32_16x16x32_bf16(aF[i], bF[j], acc[i][j], 0, 0, 0);
    }
    __syncthreads();
  }
  // ---- vT path: transpose through LDS, coalesced stores ----
  if (mode == 6 && bn >= 16) {
    u16* T = As;  // 64 x 68 pitch
    for (int i = 0; i < 2; ++i)
      for (int j = 0; j < 2; ++j)
        for (int g = 0; g < 4; ++g) {
          int rl = wm + i * 16 + quad * 4 + g;     // local m
          int cl = wn + j * 16 + l16;              // local c (d)
          T[cl * 68 + rl] = f2b(acc[i][j][g]);
        }
    __syncthreads();
    int s = bm >> 1, mb = (bm & 1) * 64;
    for (int p = 0; p < 2; ++p) {
      int c2 = tid + p * 256;                      // 0..511
      int row = c2 >> 3, cc8 = c2 & 7;             // row: local d, cc8: m-chunk
      uint4 v = *(uint4*)(T + row * 68 + cc8 * 8);
      int cg = bn * 64 + row - 1024;
      int hh = cg >> 7, d = cg & 127;
      *(uint4*)(outb3 + ((size_t)((s * 4 + hh) * 128 + d)) * 128 + mb + cc8 * 8) = v;
    }
    return;
  }
  float ls1 = 0.f, ls2 = 0.f;
  for (int i = 0; i < 2; ++i)
    for (int j = 0; j < 2; ++j)
      for (int g = 0; g < 4; ++g) {
        int rl = wm + i * 16 + quad * 4 + g;
        int r = bm * 64 + rl;
        int c = bn * 64 + wn + j * 16 + l16;
        float a = acc[i][j][g];
        if (mode == 1) {
          float gg = gelu_f(a) * svalid[rl];
          outf[(size_t)r * 128 + c] = gg;
          outb[(size_t)r * 128 + c] = f2b(gg);
        } else if (mode == 4 || mode == 5) {
          float add = (mode == 5) ? gelu_f(a) : a;
          float vl = valid[r];
          float hv = hin[(size_t)r * 128 + c];
          if (hst) hv = (hv - hmean) * hinv * vl;
          float u = hv + add * vl;
          outf[(size_t)r * 128 + c] = u;
          ls1 += u; ls2 += u * u;
        } else { // mode 6, q/k parts
          int s = r >> 7, m = r & 127;
          if (c < 512) {
            int hh = c >> 7, d = c & 127;
            outb[(size_t)(((s * 4 + hh) * 128 + m)) * 128 + d] = f2b(a);
          } else {
            int c2 = c - 512, hh = c2 >> 7, d = c2 & 127;
            outb2[(size_t)(((s * 4 + hh) * 128 + m)) * 128 + d] = f2b(a);
          }
        }
      }
  if (mode == 4 || mode == 5) {
    for (int off = 1; off < 64; off <<= 1) {
      ls1 += __shfl_xor(ls1, off, 64);
      ls2 += __shfl_xor(ls2, off, 64);
    }
    if (lane == 0) { red[wave * 2] = ls1; red[wave * 2 + 1] = ls2; }
    __syncthreads();
    if (tid == 0) {
      float S1 = red[0] + red[2] + red[4] + red[6];
      float S2 = red[1] + red[3] + red[5] + red[7];
      atomicAdd(stats + sset * 2, S1);
      atomicAdd(stats + sset * 2 + 1, S2);
    }
  }
}

// ---------------------------------------------------------------------------
// Attention, half-split: block = (set, head, q-half of 64 rows). 384 blocks.
// LDS 52 KB -> 3 blocks/CU. q,k:[s][h][m][d]; vT:[s][h][d][n]; o->[6144][512].
// Size-trimmed: skip k-tiles >= ceil(sz/16); PV K-tiles >= ceil(sz/32) are 0.
// ---------------------------------------------------------------------------
__global__ __launch_bounds__(256) void attn_kernel(
    const u16* __restrict__ qg, const u16* __restrict__ kg,
    const u16* __restrict__ vTg, u16* __restrict__ og,
    const int* __restrict__ xsize)
{
  __shared__ __align__(16) u16 bufQ[64 * 136];
  __shared__ __align__(16) u16 bufK[128 * 136];
  int tid = threadIdx.x, wave = tid >> 6, lane = tid & 63, quad = lane >> 4, l16 = lane & 15;
  int bid2 = blockIdx.x;
  int half = bid2 & 1, bh = bid2 >> 1;
  int s = bh >> 2, hh = bh & 3;
  int sz = xsize[s]; if (sz < 1) sz = 1;
  int Mt = (sz + 15) >> 4;
  int Mk = (sz + 31) >> 5;
  int MqT = Mt - half * 4;
  if (MqT <= 0) return;
  if (MqT > 4) MqT = 4;
  size_t base = (size_t)bh * 16384;
  for (int t = 0; t < 4; ++t) {
    int ch = tid + t * 256; int r = ch >> 4, cc = ch & 15;
    *(uint4*)(bufQ + r * 136 + cc * 8) =
        *(const uint4*)(qg + base + (half * 64 + r) * 128 + cc * 8);
  }
  for (int t = 0; t < 8; ++t) {
    if (t < Mt) {
      int ch = tid + t * 256; int r = ch >> 4, cc = ch & 15;
      *(uint4*)(bufK + r * 136 + cc * 8) = *(const uint4*)(kg + base + r * 128 + cc * 8);
    }
  }
  __syncthreads();
  bool act = wave < MqT;
  f32x4 acc[8] = {};
  if (act) {
    for (int ks = 0; ks < 4; ++ks) {
      bf16x8 aF = *(const bf16x8*)(bufQ + (wave * 16 + l16) * 136 + ks * 32 + quad * 8);
      bf16x8 bF[8];
#pragma unroll
      for (int j = 0; j < 8; ++j)
        if (j < Mt) bF[j] = *(const bf16x8*)(bufK + (j * 16 + l16) * 136 + ks * 32 + quad * 8);
#pragma unroll
      for (int j = 0; j < 8; ++j)
        if (j < Mt) acc[j] = __builtin_amdgcn_mfma_f32_16x16x32_bf16(aF, bF[j], acc[j], 0, 0, 0);
    }
  }
  const float rs = 0.08838834764831845f;
  if (act) {
    for (int g = 0; g < 4; ++g) {
      int rl = wave * 16 + quad * 4 + g;
      float vals[8]; float rmax = -1e30f;
#pragma unroll
      for (int j = 0; j < 8; ++j)
        if (j < Mt) {
          float v = acc[j][g] * rs;
          vals[j] = v;
          rmax = fmaxf(rmax, v);
        }
      for (int off = 1; off < 16; off <<= 1) rmax = fmaxf(rmax, __shfl_xor(rmax, off, 64));
      if (sz < 128) rmax = fmaxf(rmax, 0.0f);   // reference max includes pad zeros
      float rsum = 0.f;
#pragma unroll
      for (int j = 0; j < 8; ++j)
        if (j < Mt) {
          float e = (vals[j] != 0.0f) ? expf(vals[j] - rmax) : 0.0f;
          vals[j] = e; rsum += e;
        }
      for (int off = 1; off < 16; off <<= 1) rsum += __shfl_xor(rsum, off, 64);
      float inv = 1.0f / (rsum + 1e-10f);
#pragma unroll
      for (int j = 0; j < 8; ++j)
        if (j < Mt) bufQ[rl * 136 + j * 16 + l16] = f2b(vals[j] * inv);
    }
  }
  __syncthreads();   // all waves done with bufK (QK^T reads)
  for (int t = 0; t < 8; ++t) {
    int ch = tid + t * 256; int r = ch >> 4, cc = ch & 15;
    *(uint4*)(bufK + r * 136 + cc * 8) = *(const uint4*)(vTg + base + r * 128 + cc * 8);
  }
  __syncthreads();
  f32x4 acc2[8] = {};
  if (act) {
    for (int ks = 0; ks < Mk; ++ks) {
      bf16x8 aF = *(const bf16x8*)(bufQ + (wave * 16 + l16) * 136 + ks * 32 + quad * 8);
      bf16x8 bF[8];
#pragma unroll
      for (int j = 0; j < 8; ++j)
        bF[j] = *(const bf16x8*)(bufK + (j * 16 + l16) * 136 + ks * 32 + quad * 8);
#pragma unroll
      for (int j = 0; j < 8; ++j)
        acc2[j] = __builtin_amdgcn_mfma_f32_16x16x32_bf16(aF, bF[j], acc2[j], 0, 0, 0);
    }
  }
  for (int j = 0; j < 8; ++j)
    for (int g = 0; g < 4; ++g) {
      int rg = s * 128 + half * 64 + wave * 16 + quad * 4 + g;
      og[(size_t)rg * 512 + hh * 128 + j * 16 + l16] = f2b(acc2[j][g]);
    }
}

// ---------------------------------------------------------------------------
// Cross-set: enumerated (j<=i) pair tiles x 4 heads = 4704 blocks (no dead
// blocks). 32x32x16 MFMA, fragment-order LDS (lane-linear, conflict-free),
// size-trimmed. leaky = 0.65x + 0.35|x|. Writes raw symmetric T[j,i,h].
// ---------------------------------------------------------------------------
__global__ __launch_bounds__(256) void cross_kernel(
    const u16* __restrict__ zg, float* __restrict__ Tbuf, const int* __restrict__ xsize)
{
  __shared__ __align__(16) u16 bufA[16384];
  __shared__ __align__(16) u16 bufB[16384];
  __shared__ float red[4];
  int tid = threadIdx.x, wave = tid >> 6, lane = tid & 63;
  int t4 = blockIdx.x;
  int pr = t4 >> 2, hh = t4 & 3;
  float jf = (97.0f - sqrtf(9409.0f - 8.0f * (float)pr)) * 0.5f;
  int j = (int)jf; if (j > 47) j = 47; if (j < 0) j = 0;
  while (j > 0 && j * 48 - (j * (j - 1)) / 2 > pr) --j;
  while ((j + 1) * 48 - ((j + 1) * j) / 2 <= pr) ++j;
  int i = j + pr - (j * 48 - (j * (j - 1)) / 2);
  int sj = xsize[j]; if (sj < 1) sj = 1;
  int si = xsize[i]; if (si < 1) si = 1;
  int MjT = (sj + 31) >> 5, MiT = (si + 31) >> 5;
  size_t basej = ((size_t)j * 4 + hh) << 14;
  size_t basei = ((size_t)i * 4 + hh) << 14;
#pragma unroll
  for (int t = 0; t < 8; ++t) {
    int c = t * 256 + tid;
    int m = c & 31, half = (c >> 5) & 1, ks = (c >> 6) & 7, g = c >> 9;
    int row = g * 32 + m, col = ks * 16 + half * 8;
    if (g < MjT) *(uint4*)(bufA + c * 8) = *(const uint4*)(zg + basej + row * 128 + col);
    if (g < MiT) *(uint4*)(bufB + c * 8) = *(const uint4*)(zg + basei + row * 128 + col);
  }
  __syncthreads();
  int gA = (wave >> 1) * 2, gB = (wave & 1) * 2;
  bool a0 = gA < MjT, a1 = (gA + 1) < MjT;
  bool b0 = gB < MiT, b1 = (gB + 1) < MiT;
  f32x16 acc[2][2] = {};
  if ((a0 || a1) && (b0 || b1)) {
    for (int ks = 0; ks < 8; ++ks) {
      bf16x8 aF[2], bF[2];
      if (a0) aF[0] = *(const bf16x8*)(bufA + ((gA    ) * 8 + ks) * 512 + lane * 8);
      if (a1) aF[1] = *(const bf16x8*)(bufA + ((gA + 1) * 8 + ks) * 512 + lane * 8);
      if (b0) bF[0] = *(const bf16x8*)(bufB + ((gB    ) * 8 + ks) * 512 + lane * 8);
      if (b1) bF[1] = *(const bf16x8*)(bufB + ((gB + 1) * 8 + ks) * 512 + lane * 8);
      if (a0 && b0) acc[0][0] = __builtin_amdgcn_mfma_f32_32x32x16_bf16(aF[0], bF[0], acc[0][0], 0, 0, 0);
      if (a0 && b1) acc[0][1] = __builtin_amdgcn_mfma_f32_32x32x16_bf16(aF[0], bF[1], acc[0][1], 0, 0, 0);
      if (a1 && b0) acc[1][0] = __builtin_amdgcn_mfma_f32_32x32x16_bf16(aF[1], bF[0], acc[1][0], 0, 0, 0);
      if (a1 && b1) acc[1][1] = __builtin_amdgcn_mfma_f32_32x32x16_bf16(aF[1], bF[1], acc[1][1], 0, 0, 0);
    }
  }
  float s1 = 0.f, s2 = 0.f;
#pragma unroll
  for (int ii = 0; ii < 2; ++ii)
#pragma unroll
    for (int jj = 0; jj < 2; ++jj)
#pragma unroll
      for (int r = 0; r < 16; ++r) {
        float a = acc[ii][jj][r];
        s1 += a; s2 += fabsf(a);
      }
  const float rs = 0.08838834764831845f;
  float tp = rs * (0.65f * s1 + 0.35f * s2);
  for (int off = 1; off < 64; off <<= 1) tp += __shfl_xor(tp, off, 64);
  if (lane == 0) red[wave] = tp;
  __syncthreads();
  if (tid == 0)
    Tbuf[((j * 48 + i) << 2) + hh] = red[0] + red[1] + red[2] + red[3];
}

// out[a][b] = sum_h T[min,max,h] * w2[h] / (size_b * 128)
__global__ __launch_bounds__(256) void final_kernel(
    const float* __restrict__ Tbuf, const float* __restrict__ w2,
    const int* __restrict__ xsize, float* __restrict__ out)
{
  int idx = blockIdx.x * 256 + threadIdx.x;
  if (idx >= 2304) return;
  int a = idx / 48, b = idx - a * 48;
  int j = a < b ? a : b, i = a < b ? b : a;
  float t = 0.f;
  for (int h = 0; h < 4; ++h) t += Tbuf[((j * 48 + i) << 2) + h] * w2[h];
  int szb = xsize[b]; if (szb < 1) szb = 1;
  out[idx] = t / ((float)szb * 128.0f);
}

// ---------------------------------------------------------------------------
extern "C" void kernel_launch(void* const* d_in, const int* in_sizes, int n_in,
                              void* d_out, int out_size, void* d_ws, size_t ws_size,
                              hipStream_t stream)
{
  const float* x     = (const float*)d_in[0];
  const int*   xsize = (const int*)d_in[1];
  const float* Wproj = (const float*)d_in[2];
  const float* Wq    = (const float*)d_in[3];
  const float* Wk    = (const float*)d_in[4];
  const float* Wv    = (const float*)d_in[5];
  const float* Whp   = (const float*)d_in[6];
  const float* Wfc   = (const float*)d_in[7];
  const float* Wc    = (const float*)d_in[8];
  const float* w2    = (const float*)d_in[9];
  float* out = (float*)d_out;

  char* ws = (char*)d_ws;
  size_t off = 0;
  auto alloc = [&](size_t bytes) -> char* {
    char* p = ws + off;
    off += (bytes + 255) & ~(size_t)255;
    return p;
  };
  u16*   wT    = (u16*)  alloc(638976 * 2);
  float* stats = (float*)alloc(384 * 4);          // 4 stages x 48 sets x {S1,S2}
  float* Tbuf  = (float*)alloc(9216 * 4);
  float* valid = (float*)alloc(6144 * 4);
  float* hf0   = (float*)alloc(6144 * 128 * 4);
  u16*   hb    = (u16*)  alloc(6144 * 128 * 2);
  float* ufA   = (float*)alloc(6144 * 128 * 4);
  float* ufB   = (float*)alloc(6144 * 128 * 4);
  u16*   qb    = (u16*)  alloc((size_t)3145728 * 2);
  u16*   kb    = (u16*)  alloc((size_t)3145728 * 2);
  u16*   vTb   = (u16*)  alloc((size_t)3145728 * 2);
  u16*   ob    = (u16*)  alloc((size_t)6144 * 512 * 2);

  float* st00 = stats +   0;
  float* st01 = stats +  96;
  float* st10 = stats + 192;
  float* st11 = stats + 288;

  prep_weights<<<2498, 256, 0, stream>>>(Wproj, Wq, Wk, Wv, Whp, Wfc, Wc, wT, stats);

  // h0 = gelu(x @ Wproj) * mask ; also computes valid[]
  gemm_bt<<<dim3(96, 2), 256, 0, stream>>>(nullptr, x, nullptr, wT,
                                           hf0, hb, nullptr, nullptr,
                                           nullptr, nullptr, valid, nullptr, xsize, 128, 1);
  // ---- layer 0 ----
  gemm_bt<<<dim3(96, 24), 256, 0, stream>>>(hb, nullptr, nullptr, wT + 16384,
                                            nullptr, qb, kb, vTb,
                                            nullptr, nullptr, valid, nullptr, xsize, 128, 6);
  attn_kernel<<<384, 256, 0, stream>>>(qb, kb, vTb, ob, xsize);
  gemm_bt<<<dim3(96, 2), 256, 0, stream>>>(ob, nullptr, nullptr, wT + 409600,
                                           ufA, nullptr, nullptr, nullptr,
                                           hf0, nullptr, valid, st00, xsize, 512, 4);
  gemm_bt<<<dim3(96, 2), 256, 0, stream>>>(nullptr, ufA, st00, wT + 540672,
                                           ufB, nullptr, nullptr, nullptr,
                                           ufA, st00, valid, st01, xsize, 128, 5);
  // ---- layer 1 ----
  gemm_bt<<<dim3(96, 24), 256, 0, stream>>>(nullptr, ufB, st01, wT + 16384 + 196608,
                                            nullptr, qb, kb, vTb,
                                            nullptr, nullptr, valid, nullptr, xsize, 128, 6);
  attn_kernel<<<384, 256, 0, stream>>>(qb, kb, vTb, ob, xsize);
  gemm_bt<<<dim3(96, 2), 256, 0, stream>>>(ob, nullptr, nullptr, wT + 409600 + 65536,
                                           ufA, nullptr, nullptr, nullptr,
                                           ufB, st01, valid, st10, xsize, 512, 4);
  gemm_bt<<<dim3(96, 2), 256, 0, stream>>>(nullptr, ufA, st10, wT + 540672 + 16384,
                                           ufB, nullptr, nullptr, nullptr,
                                           ufA, st10, valid, st11, xsize, 128, 5);
  // ---- z = h @ Wc (q-layout), cross, final ----
  gemm_bt<<<dim3(96, 8), 256, 0, stream>>>(nullptr, ufB, st11, wT + 573440,
                                           nullptr, qb, nullptr, nullptr,
                                           nullptr, nullptr, valid, nullptr, xsize, 128, 6);
  cross_kernel<<<4704, 256, 0, stream>>>(qb, Tbuf, xsize);
  final_kernel<<<9, 256, 0, stream>>>(Tbuf, w2, xsize, out);
}

// Round 6
// 272.965 us; speedup vs baseline: 2.3490x; 1.0270x over previous
//
#include <hip/hip_runtime.h>
#include <hip/hip_bf16.h>
#include <math.h>

typedef unsigned short u16;
typedef short bf16x8 __attribute__((ext_vector_type(8)));
typedef float f32x4 __attribute__((ext_vector_type(4)));
typedef float f32x16 __attribute__((ext_vector_type(16)));

__device__ __forceinline__ u16 f2b(float f){
  union { float f; unsigned u; } c; c.f = f;
  unsigned u = c.u;
  unsigned r = (u + 0x7fffu + ((u >> 16) & 1u)) >> 16;
  return (u16)r;
}
__device__ __forceinline__ unsigned pack2(float a, float b){
  return (unsigned)f2b(a) | ((unsigned)f2b(b) << 16);
}
__device__ __forceinline__ float gelu_f(float x){
  return 0.5f * x * (1.0f + erff(x * 0.70710678118654752f));
}

// ---------------------------------------------------------------------------
// Weight prep -> bf16 [N][K] row-major.
// wT layout (u16): WprojT@0 (128x128) | QKVT@16384 (2 x [1536][128], rows
// 0-511 Wq^T, 512-1023 Wk^T, 1024-1535 Wv^T) | WhT@409600 (2 x [128][512]) |
// WfcT@540672 (2 x [128][128]) | WcT@573440 ([512][128]).
// ---------------------------------------------------------------------------
__global__ __launch_bounds__(256) void prep_weights(
    const float* __restrict__ Wproj, const float* __restrict__ Wq,
    const float* __restrict__ Wk,    const float* __restrict__ Wv,
    const float* __restrict__ Whp,   const float* __restrict__ Wfc,
    const float* __restrict__ Wc,    u16* __restrict__ wT)
{
  int gid = blockIdx.x * 256 + threadIdx.x;
  if (gid >= 638976) return;
  float val;
  if (gid < 16384) {
    int n = gid >> 7, k = gid & 127;
    val = Wproj[k * 128 + n];
  } else if (gid < 409600) {               // fused QKV^T
    int o = gid - 16384; int l = o / 196608, oo = o - l * 196608;
    int n = oo >> 7, k = oo & 127;
    if (n < 512)       val = Wq[l * 65536 + k * 512 + n];
    else if (n < 1024) val = Wk[l * 65536 + k * 512 + (n - 512)];
    else               val = Wv[l * 65536 + k * 512 + (n - 1024)];
  } else if (gid < 540672) {               // WhT[l][n][k], in [512][128]
    int o = gid - 409600; int l = o >> 16, oo = o & 65535;
    int n = oo >> 9, k = oo & 511;
    val = Whp[l * 65536 + k * 128 + n];
  } else if (gid < 573440) {               // WfcT
    int o = gid - 540672; int l = o >> 14, oo = o & 16383;
    int n = oo >> 7, k = oo & 127;
    val = Wfc[l * 16384 + k * 128 + n];
  } else {                                 // WcT[n][k], in [128][512]
    int o = gid - 573440; int n = o >> 7, k = o & 127;
    val = Wc[k * 512 + n];
  }
  wT[gid] = f2b(val);
}

// ---------------------------------------------------------------------------
// Trunk helpers (512-thread block, 8 waves).
// Plain GEMM 128x128x128: wave grid 4x2 -> each wave 2 m-tiles x 4 n-tiles
// (amortizes A+B LDS reads: 24 b128 per 32 MFMA).
// ---------------------------------------------------------------------------
__device__ __forceinline__ void stage_b(const u16* __restrict__ src, int pitch,
                                        u16* dst, int tid){
#pragma unroll
  for (int it = 0; it < 4; ++it){
    int ch = tid + it * 512; int r = ch >> 4, cc = ch & 15;
    *(uint4*)(dst + r * 136 + cc * 8) = *(const uint4*)(src + (size_t)r * pitch + cc * 8);
  }
}

__device__ __forceinline__ void plain_gemm(const u16* __restrict__ A,
    const u16* __restrict__ B, f32x4 (*acc)[4], int wr, int wc, int quad, int l16){
#pragma unroll
  for (int ks = 0; ks < 4; ++ks){
    bf16x8 aF[2], bF[4];
#pragma unroll
    for (int i = 0; i < 2; ++i)
      aF[i] = *(const bf16x8*)(A + ((wr*2+i)*16 + l16)*136 + ks*32 + quad*8);
#pragma unroll
    for (int n = 0; n < 4; ++n)
      bF[n] = *(const bf16x8*)(B + ((wc*4+n)*16 + l16)*136 + ks*32 + quad*8);
#pragma unroll
    for (int i = 0; i < 2; ++i)
#pragma unroll
      for (int n = 0; n < 4; ++n)
        acc[i][n] = __builtin_amdgcn_mfma_f32_16x16x32_bf16(aF[i], bF[n], acc[i][n], 0, 0, 0);
  }
}

__device__ __forceinline__ void write_rm(u16* dst, f32x4 (*acc)[4],
                                         int wr, int wc, int quad, int l16){
#pragma unroll
  for (int i = 0; i < 2; ++i)
#pragma unroll
    for (int n = 0; n < 4; ++n)
#pragma unroll
      for (int g = 0; g < 4; ++g)
        dst[((wr*2+i)*16 + quad*4 + g)*136 + (wc*4+n)*16 + l16] = f2b(acc[i][n][g]);
}

__device__ __forceinline__ void write_tr(u16* dst, f32x4 (*acc)[4],
                                         int wr, int wc, int quad, int l16){
#pragma unroll
  for (int i = 0; i < 2; ++i)
#pragma unroll
    for (int n = 0; n < 4; ++n)
#pragma unroll
      for (int g = 0; g < 4; ++g)
        dst[((wc*4+n)*16 + l16)*136 + (wr*2+i)*16 + quad*4 + g] = f2b(acc[i][n][g]);
}

__device__ __forceinline__ void block_reduce2(float &s1, float &s2,
                                              float* red, int wv, int lane){
#pragma unroll
  for (int off = 1; off < 64; off <<= 1){
    s1 += __shfl_xor(s1, off, 64);
    s2 += __shfl_xor(s2, off, 64);
  }
  if (lane == 0){ red[wv*2] = s1; red[wv*2+1] = s2; }
  __syncthreads();
  s1 = red[0]+red[2]+red[4]+red[6]+red[8]+red[10]+red[12]+red[14];
  s2 = red[1]+red[3]+red[5]+red[7]+red[9]+red[11]+red[13]+red[15];
  __syncthreads();
}

// ---------------------------------------------------------------------------
// The set-local trunk: one block per set (48 blocks x 512 threads).
// proj -> 2 x (QKV -> attn -> o@Wh -> set_norm -> Wfc -> set_norm) -> z.
// All intermediates in LDS/registers; h kept in f32 regs for residuals.
// LDS: hA (h bf16), kB (k / P), vB (q-bounce / v^T / o), wS (weight stage).
// ---------------------------------------------------------------------------
__global__ __launch_bounds__(512) void trunk(
    const float* __restrict__ x, const int* __restrict__ xsize,
    const u16* __restrict__ wT, u16* __restrict__ zg)
{
  __shared__ __align__(16) u16 hA[128*136];
  __shared__ __align__(16) u16 kB[128*136];
  __shared__ __align__(16) u16 vB[128*136];
  __shared__ __align__(16) u16 wS[128*136];
  __shared__ float svalid[128];
  __shared__ float red[16];
  int tid = threadIdx.x;
  int wv = tid >> 6, lane = tid & 63, quad = lane >> 4, l16 = lane & 15;
  int wr = wv >> 1, wc = wv & 1;
  int s = blockIdx.x;
  int sz = xsize[s]; if (sz < 1) sz = 1;
  int Mt = (sz + 15) >> 4, Mk = (sz + 31) >> 5;
  const float rs = 0.08838834764831845f;  // 1/sqrt(128)
  float den = (float)sz * 128.0f;

  // ---- stage x -> hA (bf16) + row validity; stage WprojT ----
#pragma unroll
  for (int it = 0; it < 4; ++it) {
    int ch = tid + it * 512; int r = ch >> 4, cc = ch & 15;
    const float* p = x + ((size_t)s * 128 + r) * 128 + cc * 8;
    float4 u0 = *(const float4*)p, u1 = *(const float4*)(p + 4);
    int nz = (u0.x!=0.f)|(u0.y!=0.f)|(u0.z!=0.f)|(u0.w!=0.f)|
             (u1.x!=0.f)|(u1.y!=0.f)|(u1.z!=0.f)|(u1.w!=0.f);
    nz |= __shfl_xor(nz,1,64); nz |= __shfl_xor(nz,2,64);
    nz |= __shfl_xor(nz,4,64); nz |= __shfl_xor(nz,8,64);
    if ((tid & 15) == 0) svalid[r] = nz ? 1.f : 0.f;
    uint4 w;
    w.x = pack2(u0.x,u0.y); w.y = pack2(u0.z,u0.w);
    w.z = pack2(u1.x,u1.y); w.w = pack2(u1.z,u1.w);
    *(uint4*)(hA + r*136 + cc*8) = w;
  }
  stage_b(wT, 128, wS, tid);
  __syncthreads();

  // ---- proj: h0 = gelu(x @ Wproj) * mask ----
  f32x4 hR[2][4] = {};
  {
    f32x4 acc[2][4] = {};
    plain_gemm(hA, wS, acc, wr, wc, quad, l16);
    __syncthreads();                       // hA reads done before overwrite
#pragma unroll
    for (int i = 0; i < 2; ++i)
#pragma unroll
      for (int n = 0; n < 4; ++n)
#pragma unroll
        for (int g = 0; g < 4; ++g) {
          int row = (wr*2+i)*16 + quad*4 + g;
          float gg = gelu_f(acc[i][n][g]) * svalid[row];
          hR[i][n][g] = gg;
          hA[row*136 + (wc*4+n)*16 + l16] = f2b(gg);
        }
    __syncthreads();
  }

  for (int l = 0; l < 2; ++l) {
    const u16* wQKV = wT + 16384 + l * 196608;
    const u16* wWh  = wT + 409600 + l * 65536;
    const u16* wWfc = wT + 540672 + l * 16384;
    f32x4 aR[2][4] = {};
    for (int hh = 0; hh < 4; ++hh) {
      // q = h @ Wq_h
      stage_b(wQKV + hh*16384, 128, wS, tid);
      __syncthreads();
      f32x4 acc[2][4] = {};
      plain_gemm(hA, wS, acc, wr, wc, quad, l16);
      __syncthreads();
      write_rm(vB, acc, wr, wc, quad, l16);
      stage_b(wQKV + 65536 + hh*16384, 128, wS, tid);   // Wk_h
      __syncthreads();
      // qA regs (A-layout); k = h @ Wk_h
      bf16x8 qA[4];
#pragma unroll
      for (int ks = 0; ks < 4; ++ks)
        qA[ks] = *(const bf16x8*)(vB + (wv*16 + l16)*136 + ks*32 + quad*8);
      f32x4 acck[2][4] = {};
      plain_gemm(hA, wS, acck, wr, wc, quad, l16);
      __syncthreads();
      write_rm(kB, acck, wr, wc, quad, l16);
      stage_b(wQKV + 131072 + hh*16384, 128, wS, tid);  // Wv_h
      __syncthreads();
      // v = h @ Wv_h -> vB transposed (VT[d][key])
      f32x4 accv[2][4] = {};
      plain_gemm(hA, wS, accv, wr, wc, quad, l16);
      __syncthreads();
      write_tr(vB, accv, wr, wc, quad, l16);
      __syncthreads();
      // QK^T + softmax (wave = 16 q-rows at m-tile wv; proven layout)
      bool act = wv < Mt;
      f32x4 sacc[8] = {};
      if (act) {
#pragma unroll
        for (int ks = 0; ks < 4; ++ks) {
          bf16x8 bF[8];
#pragma unroll
          for (int j = 0; j < 8; ++j)
            if (j < Mt) bF[j] = *(const bf16x8*)(kB + (j*16+l16)*136 + ks*32 + quad*8);
#pragma unroll
          for (int j = 0; j < 8; ++j)
            if (j < Mt) sacc[j] = __builtin_amdgcn_mfma_f32_16x16x32_bf16(qA[ks], bF[j], sacc[j], 0, 0, 0);
        }
        for (int g = 0; g < 4; ++g) {
          float vals[8]; float rmax = -1e30f;
#pragma unroll
          for (int j = 0; j < 8; ++j)
            if (j < Mt) {
              float v = sacc[j][g] * rs;
              vals[j] = v;
              rmax = fmaxf(rmax, v);
            }
          for (int off = 1; off < 16; off <<= 1) rmax = fmaxf(rmax, __shfl_xor(rmax, off, 64));
          if (sz < 128) rmax = fmaxf(rmax, 0.0f);   // ref max includes pad zeros
          float rsum = 0.f;
#pragma unroll
          for (int j = 0; j < 8; ++j)
            if (j < Mt) {
              float e = (vals[j] != 0.0f) ? expf(vals[j] - rmax) : 0.0f;
              vals[j] = e; rsum += e;
            }
          for (int off = 1; off < 16; off <<= 1) rsum += __shfl_xor(rsum, off, 64);
          float inv = 1.0f / (rsum + 1e-10f);
#pragma unroll
          for (int j = 0; j < 8; ++j)
            if (j < Mt) sacc[j][g] = vals[j] * inv;   // stash P in sacc
        }
      }
      __syncthreads();                       // all QK^T reads of kB done
      if (act) {
#pragma unroll
        for (int j = 0; j < 8; ++j)
          if (j < Mt)
#pragma unroll
            for (int g = 0; g < 4; ++g)
              kB[(wv*16 + quad*4 + g)*136 + j*16 + l16] = f2b(sacc[j][g]);
      }
      stage_b(wWh + hh*128, 512, wS, tid);   // WhT_h slice
      __syncthreads();
      // PV: o = P @ V  (junk P cols beyond Mt*16 are nulled by zero v rows)
      f32x4 oacc[8] = {};
      if (act) {
        for (int ks = 0; ks < Mk; ++ks) {
          bf16x8 aF = *(const bf16x8*)(kB + (wv*16 + l16)*136 + ks*32 + quad*8);
          bf16x8 bF[8];
#pragma unroll
          for (int n = 0; n < 8; ++n)
            bF[n] = *(const bf16x8*)(vB + (n*16+l16)*136 + ks*32 + quad*8);
#pragma unroll
          for (int n = 0; n < 8; ++n)
            oacc[n] = __builtin_amdgcn_mfma_f32_16x16x32_bf16(aF, bF[n], oacc[n], 0, 0, 0);
        }
      }
      __syncthreads();                       // all PV reads of vB done
#pragma unroll
      for (int n = 0; n < 8; ++n)
#pragma unroll
        for (int g = 0; g < 4; ++g)
          vB[(wv*16 + quad*4 + g)*136 + n*16 + l16] = f2b(oacc[n][g]);
      __syncthreads();
      // aR += o @ Wh_h
      plain_gemm(vB, wS, aR, wr, wc, quad, l16);
      __syncthreads();
    } // heads

    // ---- set_norm(h + a) ----
    {
      float ls1 = 0.f, ls2 = 0.f;
#pragma unroll
      for (int i = 0; i < 2; ++i)
#pragma unroll
        for (int n = 0; n < 4; ++n)
#pragma unroll
          for (int g = 0; g < 4; ++g) {
            int row = (wr*2+i)*16 + quad*4 + g;
            float u = hR[i][n][g] + aR[i][n][g] * svalid[row];
            hR[i][n][g] = u;
            ls1 += u; ls2 += u * u;
          }
      block_reduce2(ls1, ls2, red, wv, lane);
      float mean = ls1 / den;
      float var = ls2 / den - mean * mean; if (var < 0.f) var = 0.f;
      float inv = 1.0f / (sqrtf(var) + 1e-8f);
#pragma unroll
      for (int i = 0; i < 2; ++i)
#pragma unroll
        for (int n = 0; n < 4; ++n)
#pragma unroll
          for (int g = 0; g < 4; ++g) {
            int row = (wr*2+i)*16 + quad*4 + g;
            float hn = (hR[i][n][g] - mean) * inv * svalid[row];
            hR[i][n][g] = hn;
            hA[row*136 + (wc*4+n)*16 + l16] = f2b(hn);
          }
      stage_b(wWfc, 128, wS, tid);
      __syncthreads();
    }
    // ---- set_norm(h + gelu(h @ Wfc) * mask) ----
    {
      f32x4 fa[2][4] = {};
      plain_gemm(hA, wS, fa, wr, wc, quad, l16);
      __syncthreads();                       // hA reads done
      float ls1 = 0.f, ls2 = 0.f;
#pragma unroll
      for (int i = 0; i < 2; ++i)
#pragma unroll
        for (int n = 0; n < 4; ++n)
#pragma unroll
          for (int g = 0; g < 4; ++g) {
            int row = (wr*2+i)*16 + quad*4 + g;
            float u = hR[i][n][g] + gelu_f(fa[i][n][g]) * svalid[row];
            hR[i][n][g] = u;
            ls1 += u; ls2 += u * u;
          }
      block_reduce2(ls1, ls2, red, wv, lane);
      float mean = ls1 / den;
      float var = ls2 / den - mean * mean; if (var < 0.f) var = 0.f;
      float inv = 1.0f / (sqrtf(var) + 1e-8f);
#pragma unroll
      for (int i = 0; i < 2; ++i)
#pragma unroll
        for (int n = 0; n < 4; ++n)
#pragma unroll
          for (int g = 0; g < 4; ++g) {
            int row = (wr*2+i)*16 + quad*4 + g;
            float hn = (hR[i][n][g] - mean) * inv * svalid[row];
            hR[i][n][g] = hn;
            hA[row*136 + (wc*4+n)*16 + l16] = f2b(hn);
          }
      __syncthreads();
    }
  } // layers

  // ---- z = h @ Wc -> global, q-layout [s][h][m][d] ----
  const u16* wWc = wT + 573440;
  for (int hh = 0; hh < 4; ++hh) {
    stage_b(wWc + hh*16384, 128, wS, tid);
    __syncthreads();
    f32x4 za[2][4] = {};
    plain_gemm(hA, wS, za, wr, wc, quad, l16);
#pragma unroll
    for (int i = 0; i < 2; ++i)
#pragma unroll
      for (int n = 0; n < 4; ++n)
#pragma unroll
        for (int g = 0; g < 4; ++g) {
          int row = (wr*2+i)*16 + quad*4 + g;
          int col = (wc*4+n)*16 + l16;
          zg[((size_t)(s*4 + hh)*128 + row)*128 + col] = f2b(za[i][n][g]);
        }
    __syncthreads();
  }
}

// ---------------------------------------------------------------------------
// Cross-set: enumerated (j<=i) pairs x 4 heads = 4704 blocks. 32x32x16 MFMA,
// fragment-order LDS (conflict-free), size-trimmed MFMA AND epilogue.
// leaky = 0.65x + 0.35|x|. Writes raw symmetric T[j,i,h].
// ---------------------------------------------------------------------------
__global__ __launch_bounds__(256) void cross_kernel(
    const u16* __restrict__ zg, float* __restrict__ Tbuf, const int* __restrict__ xsize)
{
  __shared__ __align__(16) u16 bufA[16384];
  __shared__ __align__(16) u16 bufB[16384];
  __shared__ float red[4];
  int tid = threadIdx.x, wave = tid >> 6, lane = tid & 63;
  int t4 = blockIdx.x;
  int pr = t4 >> 2, hh = t4 & 3;
  float jf = (97.0f - sqrtf(9409.0f - 8.0f * (float)pr)) * 0.5f;
  int j = (int)jf; if (j > 47) j = 47; if (j < 0) j = 0;
  while (j > 0 && j * 48 - (j * (j - 1)) / 2 > pr) --j;
  while ((j + 1) * 48 - ((j + 1) * j) / 2 <= pr) ++j;
  int i = j + pr - (j * 48 - (j * (j - 1)) / 2);
  int sj = xsize[j]; if (sj < 1) sj = 1;
  int si = xsize[i]; if (si < 1) si = 1;
  int MjT = (sj + 31) >> 5, MiT = (si + 31) >> 5;
  size_t basej = ((size_t)j * 4 + hh) << 14;
  size_t basei = ((size_t)i * 4 + hh) << 14;
#pragma unroll
  for (int t = 0; t < 8; ++t) {
    int c = t * 256 + tid;
    int m = c & 31, half = (c >> 5) & 1, ks = (c >> 6) & 7, g = c >> 9;
    int row = g * 32 + m, col = ks * 16 + half * 8;
    if (g < MjT) *(uint4*)(bufA + c * 8) = *(const uint4*)(zg + basej + row * 128 + col);
    if (g < MiT) *(uint4*)(bufB + c * 8) = *(const uint4*)(zg + basei + row * 128 + col);
  }
  __syncthreads();
  int gA = (wave >> 1) * 2, gB = (wave & 1) * 2;
  bool a0 = gA < MjT, a1 = (gA + 1) < MjT;
  bool b0 = gB < MiT, b1 = (gB + 1) < MiT;
  f32x16 acc[2][2] = {};
  if ((a0 || a1) && (b0 || b1)) {
    for (int ks = 0; ks < 8; ++ks) {
      bf16x8 aF[2], bF[2];
      if (a0) aF[0] = *(const bf16x8*)(bufA + ((gA    ) * 8 + ks) * 512 + lane * 8);
      if (a1) aF[1] = *(const bf16x8*)(bufA + ((gA + 1) * 8 + ks) * 512 + lane * 8);
      if (b0) bF[0] = *(const bf16x8*)(bufB + ((gB    ) * 8 + ks) * 512 + lane * 8);
      if (b1) bF[1] = *(const bf16x8*)(bufB + ((gB + 1) * 8 + ks) * 512 + lane * 8);
      if (a0 && b0) acc[0][0] = __builtin_amdgcn_mfma_f32_32x32x16_bf16(aF[0], bF[0], acc[0][0], 0, 0, 0);
      if (a0 && b1) acc[0][1] = __builtin_amdgcn_mfma_f32_32x32x16_bf16(aF[0], bF[1], acc[0][1], 0, 0, 0);
      if (a1 && b0) acc[1][0] = __builtin_amdgcn_mfma_f32_32x32x16_bf16(aF[1], bF[0], acc[1][0], 0, 0, 0);
      if (a1 && b1) acc[1][1] = __builtin_amdgcn_mfma_f32_32x32x16_bf16(aF[1], bF[1], acc[1][1], 0, 0, 0);
    }
  }
  float s1 = 0.f, s2 = 0.f;
#pragma unroll
  for (int ii = 0; ii < 2; ++ii)
#pragma unroll
    for (int jj = 0; jj < 2; ++jj) {
      bool tact = (ii ? a1 : a0) && (jj ? b1 : b0);
      if (tact)
#pragma unroll
        for (int r = 0; r < 16; ++r) {
          float a = acc[ii][jj][r];
          s1 += a; s2 += fabsf(a);
        }
    }
  const float rs = 0.08838834764831845f;
  float tp = rs * (0.65f * s1 + 0.35f * s2);
  for (int off = 1; off < 64; off <<= 1) tp += __shfl_xor(tp, off, 64);
  if (lane == 0) red[wave] = tp;
  __syncthreads();
  if (tid == 0)
    Tbuf[((j * 48 + i) << 2) + hh] = red[0] + red[1] + red[2] + red[3];
}

// out[a][b] = sum_h T[min,max,h] * w2[h] / (size_b * 128)
__global__ __launch_bounds__(256) void final_kernel(
    const float* __restrict__ Tbuf, const float* __restrict__ w2,
    const int* __restrict__ xsize, float* __restrict__ out)
{
  int idx = blockIdx.x * 256 + threadIdx.x;
  if (idx >= 2304) return;
  int a = idx / 48, b = idx - a * 48;
  int j = a < b ? a : b, i = a < b ? b : a;
  float t = 0.f;
  for (int h = 0; h < 4; ++h) t += Tbuf[((j * 48 + i) << 2) + h] * w2[h];
  int szb = xsize[b]; if (szb < 1) szb = 1;
  out[idx] = t / ((float)szb * 128.0f);
}

// ---------------------------------------------------------------------------
extern "C" void kernel_launch(void* const* d_in, const int* in_sizes, int n_in,
                              void* d_out, int out_size, void* d_ws, size_t ws_size,
                              hipStream_t stream)
{
  const float* x     = (const float*)d_in[0];
  const int*   xsize = (const int*)d_in[1];
  const float* Wproj = (const float*)d_in[2];
  const float* Wq    = (const float*)d_in[3];
  const float* Wk    = (const float*)d_in[4];
  const float* Wv    = (const float*)d_in[5];
  const float* Whp   = (const float*)d_in[6];
  const float* Wfc   = (const float*)d_in[7];
  const float* Wc    = (const float*)d_in[8];
  const float* w2    = (const float*)d_in[9];
  float* out = (float*)d_out;

  char* ws = (char*)d_ws;
  size_t off = 0;
  auto alloc = [&](size_t bytes) -> char* {
    char* p = ws + off;
    off += (bytes + 255) & ~(size_t)255;
    return p;
  };
  u16*   wT   = (u16*)  alloc(638976 * 2);
  float* Tbuf = (float*)alloc(9216 * 4);
  u16*   zg   = (u16*)  alloc((size_t)3145728 * 2);

  prep_weights<<<2496, 256, 0, stream>>>(Wproj, Wq, Wk, Wv, Whp, Wfc, Wc, wT);
  trunk<<<48, 512, 0, stream>>>(x, xsize, wT, zg);
  cross_kernel<<<4704, 256, 0, stream>>>(zg, Tbuf, xsize);
  final_kernel<<<9, 256, 0, stream>>>(Tbuf, w2, xsize, out);
}